// Round 6
// baseline (469.460 us; speedup 1.0000x reference)
//
#include <hip/hip_runtime.h>
#include <hip/hip_bf16.h>
#include <math.h>

#define T_DIM 2048
#define K_DIM 17
#define HID   64
#define B_DIM 32
#define TT    8                       // output t's per workgroup

typedef short s16x8 __attribute__((ext_vector_type(8)));
typedef short s16x4 __attribute__((ext_vector_type(4)));
typedef int   i32x4 __attribute__((ext_vector_type(4)));
typedef unsigned u32x2 __attribute__((ext_vector_type(2)));
typedef float f32x4 __attribute__((ext_vector_type(4)));

__device__ __forceinline__ float bf2f(short u) {
    unsigned v = ((unsigned)(unsigned short)u) << 16;
    return __builtin_bit_cast(float, v);
}
__device__ __forceinline__ short f2bf(float f) {          // cold path
    __hip_bfloat16 h = __float2bfloat16(f);
    return __builtin_bit_cast(short, h);
}
__device__ __forceinline__ unsigned pk2bf(float lo, float hi) {
    unsigned ul = __builtin_bit_cast(unsigned, lo);
    unsigned uh = __builtin_bit_cast(unsigned, hi);
    return ((ul + 0x8000u) >> 16) | ((uh + 0x8000u) & 0xFFFF0000u);
}
// opaque register pin: forces the loaded fragment to stay materialized
__device__ __forceinline__ void pin(s16x8& v) {
    i32x4 t = __builtin_bit_cast(i32x4, v);
    asm volatile("" : "+v"(t));
    v = __builtin_bit_cast(s16x8, t);
}

// COCO skeleton sparsity: column-v nonzeros of adj (incl. self).
__device__ const int d_NBR_PTR[18] = {0,3,6,9,11,13,17,21,24,27,29,31,34,37,40,43,45,47};
__device__ const int d_NBR_K[47] = {
    0,1,2,  0,1,3,  0,2,4,  1,3,  2,4,
    5,6,7,11,  5,6,8,12,  5,7,9,  6,8,10,  7,9,  8,10,
    5,11,13,  6,12,14,  11,13,15,  12,14,16,  13,15,  14,16 };
static constexpr int NBR_PTR[18] = {0,3,6,9,11,13,17,21,24,27,29,31,34,37,40,43,45,47};
static constexpr int NBR_K[47] = {
    0,1,2,  0,1,3,  0,2,4,  1,3,  2,4,
    5,6,7,11,  5,6,8,12,  5,7,9,  6,8,10,  7,9,  8,10,
    5,11,13,  6,12,14,  11,13,15,  12,14,16,  13,15,  14,16 };

// ---------------------------------------------------------------------------
// Fold GCN channel-mix into temporal conv weights (bf16).
//   effT0[o][k32]  k = dt*8+cin (cin<3, dt<3), rest 0    (block1, K=32)
//   effT12[blk][o][dt*64+c]                              (blocks 2,3, K=192)
//   bnc[blk*64+o] = s/sqrt(v+eps);  bnc[192+blk*64+o] = b - m*inv
// ---------------------------------------------------------------------------
__global__ void fold_weights_kernel(
    const float* __restrict__ gw0, const float* __restrict__ gw1,
    const float* __restrict__ gw2, const float* __restrict__ tcn,
    const float* __restrict__ bns, const float* __restrict__ bnb,
    const float* __restrict__ bnm, const float* __restrict__ bnv,
    short* __restrict__ effT0, short* __restrict__ effT12,
    float* __restrict__ bnc)
{
    int tid = blockIdx.x * blockDim.x + threadIdx.x;
    int stride = gridDim.x * blockDim.x;
    for (int idx = tid; idx < 2048; idx += stride) {
        int o = idx >> 5, k = idx & 31, dt = k >> 3, cin = k & 7;
        float s = 0.f;
        if (dt < 3 && cin < 3)
            for (int m = 0; m < 64; m++)
                s += gw0[cin * 64 + m] * tcn[(o * 64 + m) * 3 + dt];
        effT0[idx] = f2bf(s);
    }
    for (int idx = tid; idx < 24576; idx += stride) {
        int blk = idx / 12288;
        int r = idx - blk * 12288;
        int o = r / 192, k = r - o * 192, dt = k >> 6, c = k & 63;
        const float* gw = blk ? gw2 : gw1;
        const float* tw = tcn + (size_t)(blk + 1) * 64 * 64 * 3;
        float s = 0.f;
        for (int m = 0; m < 64; m++)
            s += gw[c * 64 + m] * tw[(o * 64 + m) * 3 + dt];
        effT12[idx] = f2bf(s);
    }
    for (int i = tid; i < 192; i += stride) {
        float inv = bns[i] * rsqrtf(bnv[i] + 1e-5f);
        bnc[i] = inv;
        bnc[192 + i] = bnb[i] - bnm[i] * inv;
    }
}

// ---------------------------------------------------------------------------
// Fully fused ST-GCN, operand-swapped GEMMs.
//   MFMA: A = weights [m=o][k] (registers, pinned), B = activations
//   [k=(dt,c)][n=(t,v)-row] read c-contiguous from LDS (b128).  D gives each
//   lane 4 consecutive o at one (t,v) row -> b64 residual read + b64 store.
//   Row algebra: yb row for activation row r is r + 17*slotoff; GEMM B-read
//   row for k-chunk kk is r + rowoff*(kk>>1) — no div/mod in addressing.
// ---------------------------------------------------------------------------
__global__ __launch_bounds__(256, 2) void stgcn_fused_kernel(
    const float* __restrict__ x, const float* __restrict__ adj,
    const short* __restrict__ effT0, const short* __restrict__ effT12,
    const float* __restrict__ bnc, float* __restrict__ part)
{
    __shared__ float adj_s[289];
    __shared__ __align__(16) float xt[16 * 51];         // 3264 B
    __shared__ __align__(16) short yb[16 * 17 * 72];    // 39168 B
    __shared__ __align__(16) short xgA[14 * 17 * 72];   // 34272 B
    __shared__ float pr[4][64];

    short* xg1st = xgA;   // alias: rows [238][40], dead after GEMM1

    const int tid = threadIdx.x;
    const int b = blockIdx.y;
    const int t0 = blockIdx.x * TT;

    const int lane = tid & 63;
    const int wave = tid >> 6;
    const int col = lane & 15;      // = D column n = (t,v)-row offset
    const int kgrp = lane >> 4;     // quad

    for (int i = tid; i < 289; i += 256) adj_s[i] = adj[i];

    // coalesced x-tile load: t in [t0-4, t0+12), 51 floats per t
    {
        const int tbase = t0 - 4;
        const float* xb = x + (size_t)(b * T_DIM + tbase) * 51;
        for (int i = tid; i < 816; i += 256) {
            int tt = tbase + i / 51;
            float v = 0.f;
            if (tt >= 0 && tt < T_DIM) v = xb[i];
            xt[i] = v;
        }
    }

    // A-fragments (weights) for GEMM1: A[m=o][k], o = mt*16+col
    s16x8 af1[4];
    #pragma unroll
    for (int mt = 0; mt < 4; mt++) {
        af1[mt] = *(const s16x8*)(effT0 + (mt * 16 + col) * 32 + kgrp * 8);
        pin(af1[mt]);
    }

    __syncthreads();

    // ---- A': gc1 from LDS x-tile, pack K=32 rows into xg1st ----
    if (tid < 238) {
        int s2 = tid / 17, j = tid - s2 * 17;
        float a9[9];
        #pragma unroll
        for (int q = 0; q < 9; q++) a9[q] = 0.f;
        int p0 = d_NBR_PTR[j], p1 = d_NBR_PTR[j + 1];
        for (int e = p0; e < p1; e++) {
            int k = d_NBR_K[e];
            float w = adj_s[k * 17 + j];
            #pragma unroll
            for (int dt = 0; dt < 3; dt++) {
                const float* xp = &xt[(s2 + dt) * 51 + k * 3];
                a9[dt * 3 + 0] += w * xp[0];
                a9[dt * 3 + 1] += w * xp[1];
                a9[dt * 3 + 2] += w * xp[2];
            }
        }
        __align__(16) unsigned ov[16];
        #pragma unroll
        for (int q = 0; q < 16; q++) ov[q] = 0u;
        #pragma unroll
        for (int dt = 0; dt < 3; dt++) {
            ov[dt * 4 + 0] = pk2bf(a9[dt * 3 + 0], a9[dt * 3 + 1]);
            ov[dt * 4 + 1] = pk2bf(a9[dt * 3 + 2], 0.f);
        }
        #pragma unroll
        for (int q = 0; q < 4; q++)
            *(int4*)&xg1st[tid * 40 + q * 8] = ((const int4*)ov)[q];
    }
    __syncthreads();

    // ---- GEMM1: block1, rows 238 (15 n-tiles), K=32 ----
    {
        f32x4 inv4[4], sh4[4];
        #pragma unroll
        for (int mt = 0; mt < 4; mt++) {
            inv4[mt] = *(const f32x4*)&bnc[mt * 16 + kgrp * 4];
            sh4[mt]  = *(const f32x4*)&bnc[192 + mt * 16 + kgrp * 4];
        }
        for (int tile = wave; tile < 15; tile += 4) {
            const int r = tile * 16 + col;
            const int me = r < 238 ? r : 237;
            s16x8 bfr = *(const s16x8*)&xg1st[me * 40 + kgrp * 8];
            f32x4 acc[4];
            #pragma unroll
            for (int mt = 0; mt < 4; mt++)
                acc[mt] = __builtin_amdgcn_mfma_f32_16x16x32_bf16(
                    af1[mt], bfr, (f32x4){0.f, 0.f, 0.f, 0.f}, 0, 0, 0);
            const int s2 = me / 17;
            const int t = t0 - 3 + s2;
            const bool rowok = (r < 238);
            const bool valid = rowok && (t >= 0) && (t < T_DIM);
            #pragma unroll
            for (int mt = 0; mt < 4; mt++) {
                u32x2 st;
                float v0 = valid ? fmaxf(acc[mt][0] * inv4[mt][0] + sh4[mt][0], 0.f) : 0.f;
                float v1 = valid ? fmaxf(acc[mt][1] * inv4[mt][1] + sh4[mt][1], 0.f) : 0.f;
                float v2 = valid ? fmaxf(acc[mt][2] * inv4[mt][2] + sh4[mt][2], 0.f) : 0.f;
                float v3 = valid ? fmaxf(acc[mt][3] * inv4[mt][3] + sh4[mt][3], 0.f) : 0.f;
                st[0] = pk2bf(v0, v1);
                st[1] = pk2bf(v2, v3);
                if (rowok)
                    *(u32x2*)&yb[(r + 17) * 72 + mt * 16 + kgrp * 4] = st;
            }
        }
    }
    __syncthreads();

    // ---- gc2: y1 -> xgA (4 channels per thread, b64 LDS ops) ----
    if (tid < 224) {
        const int s2 = tid >> 4, cq = tid & 15;
        float yv[17][4];
        #pragma unroll
        for (int k = 0; k < 17; k++) {
            s16x4 u = *(const s16x4*)&yb[((s2 + 1) * 17 + k) * 72 + cq * 4];
            yv[k][0] = bf2f(u[0]); yv[k][1] = bf2f(u[1]);
            yv[k][2] = bf2f(u[2]); yv[k][3] = bf2f(u[3]);
        }
        #pragma unroll
        for (int v = 0; v < 17; v++) {
            float g0 = 0.f, g1 = 0.f, g2 = 0.f, g3 = 0.f;
            #pragma unroll
            for (int e = NBR_PTR[v]; e < NBR_PTR[v + 1]; e++) {
                int k = NBR_K[e];
                float w = adj_s[k * 17 + v];
                g0 += w * yv[k][0]; g1 += w * yv[k][1];
                g2 += w * yv[k][2]; g3 += w * yv[k][3];
            }
            u32x2 st; st[0] = pk2bf(g0, g1); st[1] = pk2bf(g2, g3);
            *(u32x2*)&xgA[(s2 * 17 + v) * 72 + cq * 4] = st;
        }
    }

    // A-fragments (weights) for GEMM2 — load while barrier drains
    s16x8 af2[6][4];
    #pragma unroll
    for (int kk = 0; kk < 6; kk++)
        #pragma unroll
        for (int mt = 0; mt < 4; mt++) {
            af2[kk][mt] = *(const s16x8*)(effT12 +
                (mt * 16 + col) * 192 + kk * 32 + kgrp * 8);
            pin(af2[kk][mt]);
        }
    __syncthreads();

    // ---- GEMM2: block2, rows 204 (13 n-tiles), K=192, DIL=1 ----
    {
        f32x4 inv4[4], sh4[4];
        #pragma unroll
        for (int mt = 0; mt < 4; mt++) {
            inv4[mt] = *(const f32x4*)&bnc[64 + mt * 16 + kgrp * 4];
            sh4[mt]  = *(const f32x4*)&bnc[256 + mt * 16 + kgrp * 4];
        }
        for (int tile = wave; tile < 13; tile += 4) {
            const int r = tile * 16 + col;
            const int me = r < 204 ? r : 203;
            f32x4 acc[4];
            #pragma unroll
            for (int mt = 0; mt < 4; mt++) acc[mt] = (f32x4){0.f, 0.f, 0.f, 0.f};
            #pragma unroll
            for (int kk = 0; kk < 6; kk++) {
                s16x8 bfr = *(const s16x8*)&xgA[
                    (me + 17 * (kk >> 1)) * 72 + (kk & 1) * 32 + kgrp * 8];
                #pragma unroll
                for (int mt = 0; mt < 4; mt++)
                    acc[mt] = __builtin_amdgcn_mfma_f32_16x16x32_bf16(
                        af2[kk][mt], bfr, acc[mt], 0, 0, 0);
            }
            const int s3 = me / 17;
            const int t = t0 - 2 + s3;
            const bool rowok = (r < 204);
            const bool valid = rowok && (t >= 0) && (t < T_DIM);
            #pragma unroll
            for (int mt = 0; mt < 4; mt++) {
                const int yi = (r + 34) * 72 + mt * 16 + kgrp * 4;
                s16x4 res = *(const s16x4*)&yb[yi];
                float v0 = valid ? fmaxf(acc[mt][0] * inv4[mt][0] + sh4[mt][0], 0.f) + bf2f(res[0]) : 0.f;
                float v1 = valid ? fmaxf(acc[mt][1] * inv4[mt][1] + sh4[mt][1], 0.f) + bf2f(res[1]) : 0.f;
                float v2 = valid ? fmaxf(acc[mt][2] * inv4[mt][2] + sh4[mt][2], 0.f) + bf2f(res[2]) : 0.f;
                float v3 = valid ? fmaxf(acc[mt][3] * inv4[mt][3] + sh4[mt][3], 0.f) + bf2f(res[3]) : 0.f;
                u32x2 st; st[0] = pk2bf(v0, v1); st[1] = pk2bf(v2, v3);
                if (rowok) *(u32x2*)&yb[yi] = st;
            }
        }
    }
    __syncthreads();

    // ---- gc3: y2 -> xgA ----
    if (tid < 192) {
        const int s3 = tid >> 4, cq = tid & 15;
        float yv[17][4];
        #pragma unroll
        for (int k = 0; k < 17; k++) {
            s16x4 u = *(const s16x4*)&yb[((s3 + 2) * 17 + k) * 72 + cq * 4];
            yv[k][0] = bf2f(u[0]); yv[k][1] = bf2f(u[1]);
            yv[k][2] = bf2f(u[2]); yv[k][3] = bf2f(u[3]);
        }
        #pragma unroll
        for (int v = 0; v < 17; v++) {
            float g0 = 0.f, g1 = 0.f, g2 = 0.f, g3 = 0.f;
            #pragma unroll
            for (int e = NBR_PTR[v]; e < NBR_PTR[v + 1]; e++) {
                int k = NBR_K[e];
                float w = adj_s[k * 17 + v];
                g0 += w * yv[k][0]; g1 += w * yv[k][1];
                g2 += w * yv[k][2]; g3 += w * yv[k][3];
            }
            u32x2 st; st[0] = pk2bf(g0, g1); st[1] = pk2bf(g2, g3);
            *(u32x2*)&xgA[(s3 * 17 + v) * 72 + cq * 4] = st;
        }
    }

    // A-fragments (weights) for GEMM3
    s16x8 af3[6][4];
    #pragma unroll
    for (int kk = 0; kk < 6; kk++)
        #pragma unroll
        for (int mt = 0; mt < 4; mt++) {
            af3[kk][mt] = *(const s16x8*)(effT12 + 12288 +
                (mt * 16 + col) * 192 + kk * 32 + kgrp * 8);
            pin(af3[kk][mt]);
        }
    __syncthreads();

    // ---- GEMM3: block3, rows 136 (9 n-tiles), K=192, DIL=2, + pool ----
    f32x4 psum[4];
    #pragma unroll
    for (int mt = 0; mt < 4; mt++) psum[mt] = (f32x4){0.f, 0.f, 0.f, 0.f};
    {
        f32x4 inv4[4], sh4[4];
        #pragma unroll
        for (int mt = 0; mt < 4; mt++) {
            inv4[mt] = *(const f32x4*)&bnc[128 + mt * 16 + kgrp * 4];
            sh4[mt]  = *(const f32x4*)&bnc[320 + mt * 16 + kgrp * 4];
        }
        for (int tile = wave; tile < 9; tile += 4) {
            const int r = tile * 16 + col;
            const int me = r < 136 ? r : 135;
            f32x4 acc[4];
            #pragma unroll
            for (int mt = 0; mt < 4; mt++) acc[mt] = (f32x4){0.f, 0.f, 0.f, 0.f};
            #pragma unroll
            for (int kk = 0; kk < 6; kk++) {
                s16x8 bfr = *(const s16x8*)&xgA[
                    (me + 34 * (kk >> 1)) * 72 + (kk & 1) * 32 + kgrp * 8];
                #pragma unroll
                for (int mt = 0; mt < 4; mt++)
                    acc[mt] = __builtin_amdgcn_mfma_f32_16x16x32_bf16(
                        af3[kk][mt], bfr, acc[mt], 0, 0, 0);
            }
            const bool rowok = (r < 136);
            #pragma unroll
            for (int mt = 0; mt < 4; mt++) {
                s16x4 res = *(const s16x4*)&yb[(r + 68) * 72 + mt * 16 + kgrp * 4];
                if (rowok) {
                    psum[mt][0] += fmaxf(acc[mt][0] * inv4[mt][0] + sh4[mt][0], 0.f) + bf2f(res[0]);
                    psum[mt][1] += fmaxf(acc[mt][1] * inv4[mt][1] + sh4[mt][1], 0.f) + bf2f(res[1]);
                    psum[mt][2] += fmaxf(acc[mt][2] * inv4[mt][2] + sh4[mt][2], 0.f) + bf2f(res[2]);
                    psum[mt][3] += fmaxf(acc[mt][3] * inv4[mt][3] + sh4[mt][3], 0.f) + bf2f(res[3]);
                }
            }
        }
    }
    // pool: reduce over the 16 n-columns (low 4 lane bits)
    #pragma unroll
    for (int off = 1; off <= 8; off <<= 1)
        #pragma unroll
        for (int mt = 0; mt < 4; mt++) {
            psum[mt][0] += __shfl_xor(psum[mt][0], off);
            psum[mt][1] += __shfl_xor(psum[mt][1], off);
            psum[mt][2] += __shfl_xor(psum[mt][2], off);
            psum[mt][3] += __shfl_xor(psum[mt][3], off);
        }
    if (col == 0)
        #pragma unroll
        for (int mt = 0; mt < 4; mt++)
            *(f32x4*)&pr[wave][mt * 16 + kgrp * 4] = psum[mt];
    __syncthreads();
    if (tid < 64)
        part[((size_t)b * 256 + blockIdx.x) * 64 + tid] =
            pr[0][tid] + pr[1][tid] + pr[2][tid] + pr[3][tid];
}

// ---------------------------------------------------------------------------
// Sum 256 partials per (b,c), mean, LayerNorm, FC. 1 wave per b.
// ---------------------------------------------------------------------------
__global__ __launch_bounds__(64) void finish_kernel(
    const float* __restrict__ part, const float* __restrict__ ln_s,
    const float* __restrict__ ln_b, const float* __restrict__ fc_w,
    const float* __restrict__ fc_b, float* __restrict__ out)
{
    const int b = blockIdx.x;
    const int c = threadIdx.x;
    float s = 0.f;
    for (int i = 0; i < 256; i++)
        s += part[((size_t)b * 256 + i) * 64 + c];
    float feat = s / (float)(T_DIM * K_DIM);

    float m = feat;
    #pragma unroll
    for (int off = 32; off > 0; off >>= 1) m += __shfl_down(m, off);
    m = __shfl(m, 0) / 64.f;
    float d = feat - m;
    float v = d * d;
    #pragma unroll
    for (int off = 32; off > 0; off >>= 1) v += __shfl_down(v, off);
    v = __shfl(v, 0) / 64.f;
    float norm = d * rsqrtf(v + 1e-5f) * ln_s[c] + ln_b[c];

    __shared__ float ns[64];
    ns[c] = norm;
    __syncthreads();
    if (c < 10) {
        float o = fc_b[c];
        for (int i = 0; i < 64; i++) o += ns[i] * fc_w[i * 10 + c];
        out[b * 10 + c] = o;
    }
}

// ---------------------------------------------------------------------------
extern "C" void kernel_launch(void* const* d_in, const int* in_sizes, int n_in,
                              void* d_out, int out_size, void* d_ws, size_t ws_size,
                              hipStream_t stream)
{
    const float* kpts = (const float*)d_in[0];
    const float* adj  = (const float*)d_in[1];
    const float* gw0  = (const float*)d_in[2];
    const float* gw1  = (const float*)d_in[3];
    const float* gw2  = (const float*)d_in[4];
    const float* tcn  = (const float*)d_in[5];
    const float* bns  = (const float*)d_in[6];
    const float* bnb  = (const float*)d_in[7];
    const float* bnm  = (const float*)d_in[8];
    const float* bnv  = (const float*)d_in[9];
    const float* lns  = (const float*)d_in[10];
    const float* lnb  = (const float*)d_in[11];
    const float* fcw  = (const float*)d_in[12];
    const float* fcb  = (const float*)d_in[13];
    float* out = (float*)d_out;

    // workspace: bnc(384 f) | part(32*256*64 f) | effT0(2048 bf16) | effT12(24576 bf16)
    float* bnc  = (float*)d_ws;
    float* part = bnc + 384;
    short* effT0  = (short*)(part + (size_t)B_DIM * 256 * 64);
    short* effT12 = effT0 + 2048;
    // total ~2.15 MB — activations never leave LDS

    fold_weights_kernel<<<64, 256, 0, stream>>>(gw0, gw1, gw2, tcn,
                                                bns, bnb, bnm, bnv,
                                                effT0, effT12, bnc);

    stgcn_fused_kernel<<<dim3(T_DIM / TT, B_DIM), 256, 0, stream>>>(
        kpts, adj, effT0, effT12, bnc, part);

    finish_kernel<<<B_DIM, 64, 0, stream>>>(part, lns, lnb, fcw, fcb, out);
}